// Round 3
// baseline (659.101 us; speedup 1.0000x reference)
//
#include <hip/hip_runtime.h>
#include <hip/hip_bf16.h>

namespace {
constexpr int kB = 16, kC = 64, kN = 1024, kT = 64;
constexpr size_t kWsNeed = (size_t)kB * kC * kN * kT * 4;  // 268435456
}

typedef short bf16x8 __attribute__((ext_vector_type(8)));
typedef float f32x4 __attribute__((ext_vector_type(4)));

__device__ __forceinline__ float tanh_fast(float x) {
    float e = __expf(2.0f * x);
    return 1.0f - 2.0f * __builtin_amdgcn_rcpf(e + 1.0f);
}

__device__ __forceinline__ unsigned short bf16_rnd(float f) {
    unsigned int u = __float_as_uint(f);
    u = (u + 0x7FFFu + ((u >> 16) & 1u)) >> 16;   // RTNE
    return (unsigned short)u;
}
__device__ __forceinline__ float bf16_to_f32(unsigned short s) {
    return __uint_as_float(((unsigned int)s) << 16);
}
__device__ __forceinline__ void split3(float v, unsigned short& h,
                                       unsigned short& m, unsigned short& l) {
    h = bf16_rnd(v);
    float r = v - bf16_to_f32(h);
    m = bf16_rnd(r);
    float r2 = r - bf16_to_f32(m);
    l = bf16_rnd(r2);
}

// packed RTNE f32->bf16 pair (dst.lo = bf16(a), dst.hi = bf16(b))
__device__ __forceinline__ unsigned int cvt_pk_bf16(float a, float b) {
    unsigned int r;
    asm("v_cvt_pk_bf16_f32 %0, %1, %2" : "=v"(r) : "v"(a), "v"(b));
    return r;
}
__device__ __forceinline__ float lof(unsigned int u) {   // low bf16 -> f32
    return __uint_as_float(u << 16);
}
__device__ __forceinline__ float hif(unsigned int u) {   // high bf16 -> f32
    return __uint_as_float(u & 0xffff0000u);
}
// 3-way split of a pair -> 3 packed words (hi, mid, lo)
__device__ __forceinline__ void split3_pk(float a, float b, unsigned int& w0,
                                          unsigned int& w1, unsigned int& w2) {
    w0 = cvt_pk_bf16(a, b);
    float ra = a - lof(w0), rb = b - hif(w0);
    w1 = cvt_pk_bf16(ra, rb);
    w2 = cvt_pk_bf16(ra - lof(w1), rb - hif(w1));
}

// ws fragment layout: element (b, nt32, t, vt, m, lane, reg) at
//   ((b*32+nt32)*131072) + (t*8 + vt*2 + m)*256 + lane*4 + reg
// 16x16x32 C/D map: col = lane&15, row = (lane>>4)*4 + reg  [m89-verified]

// ---------------- Kernel A: xw = w1 @ x + (b1 + b2), fp32 VALU ----------------
__global__ __launch_bounds__(256, 2) void xw_gemm(
    const float* __restrict__ x, const float* __restrict__ w1,
    const float* __restrict__ b1, const float* __restrict__ b2,
    float* __restrict__ ws)
{
    __shared__ __align__(16) float w1t[64][72];      // [f][v]
    __shared__ __align__(16) float xs[16][32][20];   // [f-chunk][n][t16 swizzled]

    const int tid = threadIdx.x;
    const int bid = blockIdx.x;
    const int tc = bid & 3;
    const int nt = (bid >> 2) & 31;
    const int b  = bid >> 7;
    const int n0 = nt * 32;

    #pragma unroll
    for (int k = 0; k < 16; ++k) {
        int idx = tid + 256 * k;
        int v = idx >> 6, f = idx & 63;
        w1t[f][v] = w1[idx];
    }

    const int vg = tid >> 5;
    const int n  = tid & 31;
    const int v0 = vg * 8;
    const int p  = (n >> 3) & 3;

    float bias[8];
    #pragma unroll
    for (int vj = 0; vj < 8; ++vj) bias[vj] = b1[v0 + vj] + b2[v0 + vj];

    float acc[8][4][4];
    #pragma unroll
    for (int vj = 0; vj < 8; ++vj)
        #pragma unroll
        for (int q = 0; q < 4; ++q)
            #pragma unroll
            for (int j = 0; j < 4; ++j) acc[vj][q][j] = bias[vj];

    for (int fc = 0; fc < 4; ++fc) {
        __syncthreads();
        #pragma unroll
        for (int r = 0; r < 8; ++r) {
            int slot = tid + 256 * r;
            int f = slot >> 7, nn = (slot >> 2) & 31, tq = slot & 3;
            const float4 xv = *reinterpret_cast<const float4*>(
                x + ((size_t)(b * 64 + fc * 16 + f) * 1024 + n0 + nn) * 64
                  + tc * 16 + tq * 4);
            int pp = (nn >> 3) & 3;
            *reinterpret_cast<float4*>(&xs[f][nn][((tq ^ pp) * 4)]) = xv;
        }
        __syncthreads();

        for (int f = 0; f < 16; ++f) {
            const int ff = fc * 16 + f;
            const float4 wA = *reinterpret_cast<const float4*>(&w1t[ff][v0]);
            const float4 wB = *reinterpret_cast<const float4*>(&w1t[ff][v0 + 4]);
            float wv[8] = {wA.x, wA.y, wA.z, wA.w, wB.x, wB.y, wB.z, wB.w};
            #pragma unroll
            for (int q = 0; q < 4; ++q) {
                const float4 xv = *reinterpret_cast<const float4*>(&xs[f][n][q * 4]);
                float xe[4] = {xv.x, xv.y, xv.z, xv.w};
                #pragma unroll
                for (int vj = 0; vj < 8; ++vj)
                    #pragma unroll
                    for (int j = 0; j < 4; ++j)
                        acc[vj][q][j] = fmaf(wv[vj], xe[j], acc[vj][q][j]);
            }
        }
    }

    const int vt  = vg >> 1;
    const int m   = n >> 4;
    const int nl  = n & 15;
    const size_t tilecol = ((size_t)(b * 32 + nt) * 64) * 2048;
    #pragma unroll
    for (int q = 0; q < 4; ++q) {
        #pragma unroll
        for (int jj = 0; jj < 4; ++jj) {
            const int t = tc * 16 + ((q ^ p) * 4) + jj;
            #pragma unroll
            for (int half = 0; half < 2; ++half) {
                const int lane = nl + 16 * ((vg & 1) * 2 + half);
                float4 o;
                o.x = acc[half * 4 + 0][q][jj];
                o.y = acc[half * 4 + 1][q][jj];
                o.z = acc[half * 4 + 2][q][jj];
                o.w = acc[half * 4 + 3][q][jj];
                size_t off = tilecol + ((size_t)t * 8 + vt * 2 + m) * 256 + lane * 4;
                *reinterpret_cast<float4*>(ws + off) = o;
            }
        }
    }
}

// ---------------- Kernel B: recurrence, 2-wave blocks, 1 barrier/step ----------------
#define T6(ACC, VT, KC) \
    ACC = __builtin_amdgcn_mfma_f32_16x16x32_bf16(aw[VT][KC][2], hb[0][KC], ACC, 0, 0, 0); \
    ACC = __builtin_amdgcn_mfma_f32_16x16x32_bf16(aw[VT][KC][0], hb[2][KC], ACC, 0, 0, 0); \
    ACC = __builtin_amdgcn_mfma_f32_16x16x32_bf16(aw[VT][KC][1], hb[1][KC], ACC, 0, 0, 0); \
    ACC = __builtin_amdgcn_mfma_f32_16x16x32_bf16(aw[VT][KC][1], hb[0][KC], ACC, 0, 0, 0); \
    ACC = __builtin_amdgcn_mfma_f32_16x16x32_bf16(aw[VT][KC][0], hb[1][KC], ACC, 0, 0, 0); \
    ACC = __builtin_amdgcn_mfma_f32_16x16x32_bf16(aw[VT][KC][0], hb[0][KC], ACC, 0, 0, 0);

#define FIN(VT, S) { \
    float h0 = tanh_fast(S[0]), h1 = tanh_fast(S[1]); \
    float h2 = tanh_fast(S[2]), h3 = tanh_fast(S[3]); \
    unsigned int p0, p1, p2, q0, q1, q2; \
    split3_pk(h0, h1, p0, p1, p2); \
    split3_pk(h2, h3, q0, q1, q2); \
    ow[VT][0][j] = p0; ow[VT][1][j] = q0; \
    const int kb = (32 * w + 16 * VT + 4 * lg) ^ knl; \
    *reinterpret_cast<uint2*>(&hsp[wbuf][0][nl][kb]) = make_uint2(p0, q0); \
    *reinterpret_cast<uint2*>(&hsp[wbuf][1][nl][kb]) = make_uint2(p1, q1); \
    *reinterpret_cast<uint2*>(&hsp[wbuf][2][nl][kb]) = make_uint2(p2, q2); }

__global__ __launch_bounds__(128, 2) void rnn_rec(
    const float* __restrict__ w2, const float* __restrict__ ws,
    float* __restrict__ out)
{
    // double-buffered h splits: [buf][split][n][k + 8 pad], XOR-swizzled k
    __shared__ __align__(16) unsigned short hsp[2][3][16][72];  // 13824 B

    const int tid  = threadIdx.x;
    const int w    = tid >> 6;         // wave id: v in [32w, 32w+32)
    const int lane = tid & 63;
    const int lg   = lane >> 4;
    const int nl   = lane & 15;
    const int knl  = (nl & 3) << 3;    // k XOR-swizzle key
    const int bid  = blockIdx.x;
    const int nt16 = bid & 63;
    const int b    = bid >> 6;
    const int m    = nt16 & 1;
    const int nt32 = nt16 >> 1;
    const int n0   = nt16 * 16;

    // zero both h buffers (h(-1) = 0)
    for (int i = tid; i < 3456; i += 128)
        reinterpret_cast<unsigned int*>(hsp)[i] = 0u;

    // A-operand: w2 row-splits. A row_local = nl, k = kc*32 + lg*8 + j.
    bf16x8 aw[2][2][3];
    #pragma unroll
    for (int vt = 0; vt < 2; ++vt) {
        #pragma unroll
        for (int kc = 0; kc < 2; ++kc) {
            const float* src = w2 + (size_t)(32 * w + 16 * vt + nl) * 64 + kc * 32 + lg * 8;
            const float4 f0 = *reinterpret_cast<const float4*>(src);
            const float4 f1 = *reinterpret_cast<const float4*>(src + 4);
            float e[8] = {f0.x, f0.y, f0.z, f0.w, f1.x, f1.y, f1.z, f1.w};
            #pragma unroll
            for (int jp = 0; jp < 4; ++jp) {
                unsigned int u0, u1, u2;
                split3_pk(e[2 * jp], e[2 * jp + 1], u0, u1, u2);
                aw[vt][kc][0][2 * jp] = (short)(u0 & 0xffffu);
                aw[vt][kc][0][2 * jp + 1] = (short)(u0 >> 16);
                aw[vt][kc][1][2 * jp] = (short)(u1 & 0xffffu);
                aw[vt][kc][1][2 * jp + 1] = (short)(u1 >> 16);
                aw[vt][kc][2][2 * jp] = (short)(u2 & 0xffffu);
                aw[vt][kc][2][2 * jp + 1] = (short)(u2 >> 16);
            }
        }
    }

    const size_t slab = (size_t)(b * 32 + nt32) * 131072;
    const float4* xq = reinterpret_cast<const float4*>(ws + slab)
                     + (size_t)m * 64 + lane + (size_t)w * 256;

    __syncthreads();

    float4 xwc0 = xq[0];       // t=0, vt=0
    float4 xwc1 = xq[128];     // t=0, vt=1
    unsigned int ow[2][2][16]; // [vt][row-pair][t-in-group] bf16-packed hi split

    for (int tg = 0; tg < 4; ++tg) {
        #pragma unroll
        for (int j = 0; j < 16; ++j) {
            const int t = tg * 16 + j;
            const int wbuf = t & 1, rbuf = wbuf ^ 1;

            // B-fragments of h(t-1)
            bf16x8 hb[3][2];
            #pragma unroll
            for (int s = 0; s < 3; ++s)
                #pragma unroll
                for (int kc = 0; kc < 2; ++kc)
                    hb[s][kc] = *reinterpret_cast<const bf16x8*>(
                        &hsp[rbuf][s][nl][(kc * 32 + lg * 8) ^ knl]);

            // prefetch next step's xw
            float4 xn0, xn1;
            const bool pf = (t < 63);
            if (pf) {
                xn0 = xq[(size_t)(t + 1) * 512];
                xn1 = xq[(size_t)(t + 1) * 512 + 128];
            }

            f32x4 a00 = {xwc0.x, xwc0.y, xwc0.z, xwc0.w};
            f32x4 a01 = {0.f, 0.f, 0.f, 0.f};
            f32x4 a10 = {xwc1.x, xwc1.y, xwc1.z, xwc1.w};
            f32x4 a11 = {0.f, 0.f, 0.f, 0.f};
            T6(a00, 0, 0) T6(a01, 0, 1) T6(a10, 1, 0) T6(a11, 1, 1)
            f32x4 s0 = a00 + a01;
            f32x4 s1 = a10 + a11;

            FIN(0, s0) FIN(1, s1)

            __syncthreads();   // h(t) visible; also guards buffer reuse

            if (pf) { xwc0 = xn0; xwc1 = xn1; }
        }

        // flush 16 timesteps: each lane writes full 64B lines per (v,n)
        #pragma unroll
        for (int vt = 0; vt < 2; ++vt) {
            #pragma unroll
            for (int rp = 0; rp < 2; ++rp) {
                const int v = 32 * w + 16 * vt + 4 * lg + 2 * rp;
                float* d0 = out + ((size_t)(b * 64 + v) * 1024 + n0 + nl) * 64 + tg * 16;
                float* d1 = d0 + 65536;   // v+1 row
                #pragma unroll
                for (int c = 0; c < 4; ++c) {
                    const unsigned int u0 = ow[vt][rp][4 * c + 0];
                    const unsigned int u1 = ow[vt][rp][4 * c + 1];
                    const unsigned int u2 = ow[vt][rp][4 * c + 2];
                    const unsigned int u3 = ow[vt][rp][4 * c + 3];
                    float4 o0 = {lof(u0), lof(u1), lof(u2), lof(u3)};
                    float4 o1 = {hif(u0), hif(u1), hif(u2), hif(u3)};
                    *reinterpret_cast<float4*>(d0 + 4 * c) = o0;
                    *reinterpret_cast<float4*>(d1 + 4 * c) = o1;
                }
            }
        }
    }
}
#undef T6
#undef FIN

// ---------------- Fallback (round-1 kernel) if ws too small ----------------
__global__ __launch_bounds__(256, 2) void rnn_fused_kernel(
    const float* __restrict__ x, const float* __restrict__ w1,
    const float* __restrict__ b1, const float* __restrict__ w2,
    const float* __restrict__ b2, float* __restrict__ out)
{
    __shared__ __align__(16) float w1t[64][65];
    __shared__ __align__(16) float w2t[64][65];
    __shared__ __align__(16) float bsum[64];
    __shared__ __align__(16) float xs[4][64][32];
    __shared__ __align__(16) float Hs[64][32];

    const int tid = threadIdx.x;
    const int bid = blockIdx.x;
    const int b   = bid >> 5;
    const int n0  = (bid & 31) * 32;

    #pragma unroll
    for (int k = 0; k < 16; ++k) {
        const int idx = tid + 256 * k;
        const int v = idx >> 6, f = idx & 63;
        w1t[f][v] = w1[idx];
        w2t[f][v] = w2[idx];
    }
    if (tid < 64) bsum[tid] = b1[tid] + b2[tid];
    #pragma unroll
    for (int k = 0; k < 8; ++k) reinterpret_cast<float*>(Hs)[tid + 256 * k] = 0.0f;
    __syncthreads();

    const int v  = tid >> 2;
    const int ng = (tid & 3) * 8;
    const float bs = bsum[v];

    for (int tg = 0; tg < 16; ++tg) {
        #pragma unroll
        for (int k = 0; k < 8; ++k) {
            const int lin = tid + 256 * k;
            const int f = lin >> 5, n = lin & 31;
            const float4 xv = *reinterpret_cast<const float4*>(
                x + ((b * 64 + f) * 1024 + n0 + n) * 64 + tg * 4);
            xs[0][f][n] = xv.x; xs[1][f][n] = xv.y; xs[2][f][n] = xv.z; xs[3][f][n] = xv.w;
        }
        __syncthreads();
        #pragma unroll
        for (int tt = 0; tt < 4; ++tt) {
            const float* hsrc = (tt == 0) ? &Hs[0][0] : &xs[tt - 1][0][0];
            float acc[8];
            #pragma unroll
            for (int j = 0; j < 8; ++j) acc[j] = bs;
            #pragma unroll 4
            for (int f = 0; f < 64; ++f) {
                const float wv = w1t[f][v];
                const float4 xa = *reinterpret_cast<const float4*>(&xs[tt][f][ng]);
                const float4 xb = *reinterpret_cast<const float4*>(&xs[tt][f][ng + 4]);
                acc[0] = fmaf(wv, xa.x, acc[0]); acc[1] = fmaf(wv, xa.y, acc[1]);
                acc[2] = fmaf(wv, xa.z, acc[2]); acc[3] = fmaf(wv, xa.w, acc[3]);
                acc[4] = fmaf(wv, xb.x, acc[4]); acc[5] = fmaf(wv, xb.y, acc[5]);
                acc[6] = fmaf(wv, xb.z, acc[6]); acc[7] = fmaf(wv, xb.w, acc[7]);
            }
            #pragma unroll 4
            for (int u = 0; u < 64; ++u) {
                const float wv = w2t[u][v];
                const float4 ha = *reinterpret_cast<const float4*>(hsrc + u * 32 + ng);
                const float4 hb2 = *reinterpret_cast<const float4*>(hsrc + u * 32 + ng + 4);
                acc[0] = fmaf(wv, ha.x, acc[0]); acc[1] = fmaf(wv, ha.y, acc[1]);
                acc[2] = fmaf(wv, ha.z, acc[2]); acc[3] = fmaf(wv, ha.w, acc[3]);
                acc[4] = fmaf(wv, hb2.x, acc[4]); acc[5] = fmaf(wv, hb2.y, acc[5]);
                acc[6] = fmaf(wv, hb2.z, acc[6]); acc[7] = fmaf(wv, hb2.w, acc[7]);
            }
            float4 o0, o1;
            o0.x = tanh_fast(acc[0]); o0.y = tanh_fast(acc[1]);
            o0.z = tanh_fast(acc[2]); o0.w = tanh_fast(acc[3]);
            o1.x = tanh_fast(acc[4]); o1.y = tanh_fast(acc[5]);
            o1.z = tanh_fast(acc[6]); o1.w = tanh_fast(acc[7]);
            __syncthreads();
            *reinterpret_cast<float4*>(&xs[tt][v][ng])     = o0;
            *reinterpret_cast<float4*>(&xs[tt][v][ng + 4]) = o1;
            if (tt == 3) {
                *reinterpret_cast<float4*>(&Hs[v][ng])     = o0;
                *reinterpret_cast<float4*>(&Hs[v][ng + 4]) = o1;
            }
            __syncthreads();
        }
        #pragma unroll
        for (int k = 0; k < 8; ++k) {
            const int lin = tid + 256 * k;
            const int vv = lin >> 5, n = lin & 31;
            float4 o;
            o.x = xs[0][vv][n]; o.y = xs[1][vv][n]; o.z = xs[2][vv][n]; o.w = xs[3][vv][n];
            *reinterpret_cast<float4*>(
                out + ((b * 64 + vv) * 1024 + n0 + n) * 64 + tg * 4) = o;
        }
        __syncthreads();
    }
}

extern "C" void kernel_launch(void* const* d_in, const int* in_sizes, int n_in,
                              void* d_out, int out_size, void* d_ws, size_t ws_size,
                              hipStream_t stream) {
    const float* x  = (const float*)d_in[0];
    const float* w1 = (const float*)d_in[1];
    const float* b1 = (const float*)d_in[2];
    const float* w2 = (const float*)d_in[3];
    const float* b2 = (const float*)d_in[4];
    float* out = (float*)d_out;

    if (ws_size >= kWsNeed) {
        float* ws = (float*)d_ws;
        hipLaunchKernelGGL(xw_gemm, dim3(2048), dim3(256), 0, stream,
                           x, w1, b1, b2, ws);
        hipLaunchKernelGGL(rnn_rec, dim3(1024), dim3(128), 0, stream,
                           w2, ws, out);
    } else {
        hipLaunchKernelGGL(rnn_fused_kernel, dim3(512), dim3(256), 0, stream,
                           x, w1, b1, w2, b2, out);
    }
}